// Round 1
// baseline (279.717 us; speedup 1.0000x reference)
//
#include <hip/hip_runtime.h>
#include <hip/hip_bf16.h>
#include <stdint.h>

typedef unsigned short u16;
typedef unsigned int   u32;
typedef __bf16 bf16x8 __attribute__((ext_vector_type(8)));
typedef float  f32x4  __attribute__((ext_vector_type(4)));

#define BATCH 32
#define CIN   128
#define HH    56
#define WW    56
#define OC    256
#define HP    58
#define WP    58
#define PLANE  (HH*WW)    // 3136
#define PPLANE (HP*WP)    // 3364
#define KDIM   1152       // CIN*9
#define NKT    36         // KDIM/32

#define XPAD_ELEMS (BATCH*CIN*PPLANE)  // 13,778,944 bf16
#define W3_ELEMS   (OC*KDIM)           // 294,912 bf16

// ---------------- prep: zero-pad + fp32->bf16 convert of x ----------------
__global__ void pad_kernel(const float* __restrict__ x, u16* __restrict__ xpad) {
    int p = blockIdx.x * blockDim.x + threadIdx.x;   // pair index
    if (p >= XPAD_ELEMS / 2) return;
    int e   = p * 2;
    int bc  = e / PPLANE;
    int rem = e - bc * PPLANE;
    int y   = rem / WP;
    int x0  = rem - y * WP;          // even, so pair stays in one row
    u32 v01 = 0;
#pragma unroll
    for (int j = 0; j < 2; ++j) {
        int xx = x0 + j;
        float val = 0.f;
        if (y >= 1 && y <= HH && xx >= 1 && xx <= WW)
            val = x[bc * PLANE + (y - 1) * WW + (xx - 1)];
        __hip_bfloat16 bv = __float2bfloat16(val);
        v01 |= ((u32)(*(u16*)&bv)) << (16 * j);
    }
    *(u32*)(xpad + e) = v01;
}

// ---- prep: repack W[OC][C*9] -> bf16 tiled  W3[nt][kt][ni(128)][ci(32)] ----
// global k ordering: k = r*128 + c  (r = kh*3+kw)
__global__ void pack_w(const float* __restrict__ W, u16* __restrict__ w3) {
    int o = blockIdx.x * blockDim.x + threadIdx.x;
    if (o >= W3_ELEMS) return;
    int nt   = o / (NKT * 4096);
    int rem  = o - nt * (NKT * 4096);
    int kt   = rem / 4096;
    int rem2 = rem - kt * 4096;
    int ni   = rem2 >> 5;
    int ci   = rem2 & 31;
    int n = nt * 128 + ni;
    int r = kt >> 2;                 // 0..8
    int c = ((kt & 3) << 5) + ci;    // 0..127
    float val = W[n * KDIM + c * 9 + r];
    __hip_bfloat16 bv = __float2bfloat16(val);
    w3[o] = *(u16*)&bv;
}

// ---------------- main: implicit GEMM, 128x128 tile, BK=32 ----------------
// MFMA A-operand = weight tile (rows = oc), B-operand = x-patch tile
// (cols = spatial m) so C/D col=lane&15 -> 16 consecutive spatial positions
// -> coalesced stores into NCHW output.
__global__ __launch_bounds__(256) void conv_main(
    const u16* __restrict__ xpad,
    const u16* __restrict__ w3,
    const float* __restrict__ bias,
    float* __restrict__ out)
{
    __shared__ __align__(16) u16 As[128 * 40];  // weights [ni][ci], stride 40
    __shared__ __align__(16) u16 Bs[128 * 40];  // x-col   [mi][ci], stride 40

    const int tid = threadIdx.x;
    const int m0  = blockIdx.x * 128;
    const int nt  = blockIdx.y;

    // B (x) staging assignment: fixed spatial row per thread, 16 channels
    const int mi = tid & 127;
    const int cg = tid >> 7;     // 0/1 -> ci base 16*cg
    const int m  = m0 + mi;
    const int b  = m / PLANE;
    const int s  = m - b * PLANE;
    const int h  = s / WW;
    const int w  = s - h * WW;
    const int pbase = b * (CIN * PPLANE) + h * WP + w;

    const u16* w3t = w3 + (size_t)nt * (NKT * 4096);

    const int lane = tid & 63;
    const int wid  = tid >> 6;
    const int wn   = wid >> 1;   // which 64 of the 128 oc
    const int wm   = wid & 1;    // which 64 of the 128 m
    const int l16  = lane & 15;
    const int quad = lane >> 4;

    f32x4 acc[4][4];
#pragma unroll
    for (int f = 0; f < 4; ++f)
#pragma unroll
        for (int g = 0; g < 4; ++g)
            acc[f][g] = (f32x4){0.f, 0.f, 0.f, 0.f};

    for (int kt = 0; kt < NKT; ++kt) {
        const int r  = kt >> 2;
        const int kh = r / 3;
        const int kw = r - kh * 3;
        const int c0 = (kt & 3) << 5;

        // gather 16 x-patch values (strided by channel plane)
        union { u32 u[8]; uint4 v[2]; } bv;
        {
            const u16* src = xpad + pbase + (c0 + cg * 16) * PPLANE + kh * WP + kw;
#pragma unroll
            for (int j = 0; j < 8; ++j) {
                u32 lo = src[(2 * j) * PPLANE];
                u32 hi = src[(2 * j + 1) * PPLANE];
                bv.u[j] = lo | (hi << 16);
            }
        }
        // weights: fully contiguous packed chunk, 32 B/thread
        uint4 a0 = *(const uint4*)(w3t + kt * 4096 + tid * 16);
        uint4 a1 = *(const uint4*)(w3t + kt * 4096 + tid * 16 + 8);

        __syncthreads();
        {
            u16* dstA = &As[(tid >> 1) * 40 + (tid & 1) * 16];
            *(uint4*)dstA       = a0;
            *(uint4*)(dstA + 8) = a1;
            u16* dstB = &Bs[mi * 40 + cg * 16];
            *(uint4*)dstB       = bv.v[0];
            *(uint4*)(dstB + 8) = bv.v[1];
        }
        __syncthreads();

        bf16x8 af[4], bfr[4];
#pragma unroll
        for (int f = 0; f < 4; ++f)
            af[f] = *(const bf16x8*)&As[(wn * 64 + f * 16 + l16) * 40 + quad * 8];
#pragma unroll
        for (int g = 0; g < 4; ++g)
            bfr[g] = *(const bf16x8*)&Bs[(wm * 64 + g * 16 + l16) * 40 + quad * 8];

#pragma unroll
        for (int f = 0; f < 4; ++f)
#pragma unroll
            for (int g = 0; g < 4; ++g)
                acc[f][g] = __builtin_amdgcn_mfma_f32_16x16x32_bf16(
                    af[f], bfr[g], acc[f][g], 0, 0, 0);
    }

    // epilogue: D row = oc (quad*4+reg), col = spatial m (lane&15)
    const int n0 = nt * 128 + wn * 64;
#pragma unroll
    for (int g = 0; g < 4; ++g) {
        const int mm = m0 + wm * 64 + g * 16 + l16;
        const int bb = mm / PLANE;
        const int ss = mm - bb * PLANE;
        float* obase = out + (size_t)bb * (OC * PLANE) + ss;
#pragma unroll
        for (int f = 0; f < 4; ++f) {
#pragma unroll
            for (int i = 0; i < 4; ++i) {
                const int n = n0 + f * 16 + quad * 4 + i;
                obase[n * PLANE] = acc[f][g][i] + bias[n];
            }
        }
    }
}

extern "C" void kernel_launch(void* const* d_in, const int* in_sizes, int n_in,
                              void* d_out, int out_size, void* d_ws, size_t ws_size,
                              hipStream_t stream) {
    const float* x    = (const float*)d_in[0];
    const float* W    = (const float*)d_in[1];
    const float* bias = (const float*)d_in[2];
    float* out = (float*)d_out;

    u16* xpad = (u16*)d_ws;
    u16* w3   = xpad + XPAD_ELEMS;

    int padPairs = XPAD_ELEMS / 2;
    pad_kernel<<<(padPairs + 255) / 256, 256, 0, stream>>>(x, xpad);
    pack_w<<<(W3_ELEMS + 255) / 256, 256, 0, stream>>>(W, w3);

    dim3 grid(784, 2);
    conv_main<<<grid, 256, 0, stream>>>(xpad, w3, bias, out);
}

// Round 3
// 227.011 us; speedup vs baseline: 1.2322x; 1.2322x over previous
//
#include <hip/hip_runtime.h>
#include <hip/hip_bf16.h>
#include <stdint.h>

typedef unsigned short u16;
typedef unsigned int   u32;
typedef __bf16 bf16x8 __attribute__((ext_vector_type(8)));
typedef float  f32x4  __attribute__((ext_vector_type(4)));

#define BATCH 32
#define CIN   128
#define HH    56
#define WW    56
#define OC    256
#define HP    58
#define WP    58
#define PLANE  (HH*WW)    // 3136
#define KDIM   1152       // CIN*9
#define NKT    36         // KDIM/32

#define XPAD_ELEMS (BATCH*HP*WP*CIN)   // NHWC padded bf16: 13,778,944
#define W3_ELEMS   (OC*KDIM)           // 294,912 bf16

#define GLDS16(g, l) __builtin_amdgcn_global_load_lds( \
    (const __attribute__((address_space(1))) void*)(g), \
    (__attribute__((address_space(3))) void*)(l), 16, 0, 0)

// ---------------- prep 0: zero xpad (borders stay zero) ----------------
__global__ void zero_ws(uint4* __restrict__ p, int n4) {
    int i = blockIdx.x * blockDim.x + threadIdx.x;
    if (i < n4) p[i] = (uint4){0, 0, 0, 0};
}

// ---- prep 1: NCHW fp32 -> NHWC bf16 interior, via LDS transpose ----
// block = (h, b); handles one (b, h): 128 ch x 56 w
__global__ __launch_bounds__(256) void pad_tr(const float* __restrict__ x,
                                              u16* __restrict__ xpad) {
    __shared__ u16 T16[56 * 130];   // [w][c], +2 pad -> bank stride 65 dwords
    const int h = blockIdx.x;
    const int b = blockIdx.y;
    const int tid = threadIdx.x;

    // read: coalesced rows of 56 floats per channel
    const float* src = x + (size_t)b * CIN * PLANE + h * WW;
#pragma unroll
    for (int j = 0; j < 28; ++j) {              // 28*256 = 7168 = 128*56
        int flat = j * 256 + tid;
        int c = flat / 56;
        int w = flat - c * 56;
        float v = src[(size_t)c * PLANE + w];
        __hip_bfloat16 bv = __float2bfloat16(v);
        T16[w * 130 + c] = *(u16*)&bv;
    }
    __syncthreads();

    // write: contiguous 56*128 bf16 = 896 uint4 (16 uint4 per w position)
    const u32* T32 = (const u32*)T16;
    uint4* dst = (uint4*)(xpad + ((size_t)(b * HP + h + 1) * WP + 1) * CIN);
#pragma unroll
    for (int j = 0; j < 4; ++j) {
        int g = j * 256 + tid;
        if (g < 896) {
            int wp = g >> 4, cq = g & 15;       // 16 uint4 = 128 ch per wp
            uint4 v;
            v.x = T32[wp * 65 + cq * 4 + 0];
            v.y = T32[wp * 65 + cq * 4 + 1];
            v.z = T32[wp * 65 + cq * 4 + 2];
            v.w = T32[wp * 65 + cq * 4 + 3];
            dst[g] = v;
        }
    }
}

// ---- prep 2: W[OC][C*9] fp32 -> bf16 tiled w3[nt][kt][ni128][ci32] ----
// k ordering: k = r*128 + c  (r = kh*3+kw)
__global__ void pack_w(const float* __restrict__ W, u16* __restrict__ w3) {
    int o = blockIdx.x * blockDim.x + threadIdx.x;
    if (o >= W3_ELEMS) return;
    int nt   = o / (NKT * 4096);
    int rem  = o - nt * (NKT * 4096);
    int kt   = rem / 4096;
    int rem2 = rem - kt * 4096;
    int ni   = rem2 >> 5;
    int ci   = rem2 & 31;
    int n = nt * 128 + ni;
    int r = kt >> 2;                 // 0..8
    int c = ((kt & 3) << 5) + ci;    // 0..127
    float val = W[n * KDIM + c * 9 + r];
    __hip_bfloat16 bv = __float2bfloat16(val);
    w3[o] = *(u16*)&bv;
}

// ---------------- main: implicit GEMM, 128x128 tile, BK=32 ----------------
// A = weights (rows = oc), B = x patches (rows = spatial m). Both tiles
// staged via global_load_lds dwordx4 (m97 structure). C/D col = lane&15 ->
// 16 consecutive spatial m -> coalesced output stores.
__global__ __launch_bounds__(256) void conv_main(
    const u16* __restrict__ xpad,
    const u16* __restrict__ w3,
    const float* __restrict__ bias,
    float* __restrict__ out)
{
    __shared__ __align__(16) u16 As[128 * 32];  // [ni][ci], 64 B rows, 8 KB
    __shared__ __align__(16) u16 Bs[128 * 32];  // [mi][ci], 64 B rows, 8 KB

    const int tid  = threadIdx.x;
    const int lane = tid & 63;
    const int wv   = tid >> 6;
    const int m0   = blockIdx.x * 128;
    const int nt   = blockIdx.y;

    // B staging: granule G = wv*128 + i*64 + lane -> row mi = G>>2, chunk = lane&3
    const int mi0 = wv * 32 + (lane >> 2);
    size_t bbase[2];
#pragma unroll
    for (int i = 0; i < 2; ++i) {
        int mi = mi0 + i * 16;
        int m  = m0 + mi;
        int bb = m / PLANE;
        int s  = m - bb * PLANE;
        int hh = s / WW;
        int ww = s - hh * WW;
        bbase[i] = ((size_t)((bb * HP + hh) * WP + ww) * CIN + (lane & 3) * 8) * 2;
    }
    const char* w3t  = (const char*)(w3 + (size_t)nt * (NKT * 4096));
    const size_t abase = (size_t)(wv * 128 + lane) * 16;   // bytes within kt block

    char* AsW = (char*)As + wv * 2048;   // this wave's DMA window
    char* BsW = (char*)Bs + wv * 2048;

    const int wn = wv >> 1, wm = wv & 1;
    const int l16 = lane & 15, quad = lane >> 4;

    f32x4 acc[4][4];
#pragma unroll
    for (int f = 0; f < 4; ++f) {
        f32x4 bv = *(const f32x4*)&bias[nt * 128 + wn * 64 + f * 16 + quad * 4];
#pragma unroll
        for (int g = 0; g < 4; ++g) acc[f][g] = bv;
    }

    for (int r = 0; r < 9; ++r) {
        const int kh = (r * 11) >> 5;          // r/3
        const int kw = r - kh * 3;
        const size_t xoff = (size_t)(kh * WP + kw) * CIN * 2;
#pragma unroll
        for (int cc = 0; cc < 4; ++cc) {
            const int kt = r * 4 + cc;
            // stage A (weights) + B (x patches) via LDS-DMA
#pragma unroll
            for (int i = 0; i < 2; ++i) {
                GLDS16(w3t + (size_t)kt * 8192 + abase + i * 1024,
                       AsW + i * 1024);
                GLDS16((const char*)xpad + bbase[i] + xoff + cc * 64,
                       BsW + i * 1024);
            }
            __syncthreads();

            bf16x8 af[4], bfr[4];
#pragma unroll
            for (int f = 0; f < 4; ++f)
                af[f] = *(const bf16x8*)&As[(wn * 64 + f * 16 + l16) * 32 + quad * 8];
#pragma unroll
            for (int g = 0; g < 4; ++g)
                bfr[g] = *(const bf16x8*)&Bs[(wm * 64 + g * 16 + l16) * 32 + quad * 8];

#pragma unroll
            for (int f = 0; f < 4; ++f)
#pragma unroll
                for (int g = 0; g < 4; ++g)
                    acc[f][g] = __builtin_amdgcn_mfma_f32_16x16x32_bf16(
                        af[f], bfr[g], acc[f][g], 0, 0, 0);
            __syncthreads();
        }
    }

    // epilogue: D row = oc (quad*4+reg), col = spatial m (lane&15)
    const int n0 = nt * 128 + wn * 64;
#pragma unroll
    for (int g = 0; g < 4; ++g) {
        const int mm = m0 + wm * 64 + g * 16 + l16;
        const int bb = mm / PLANE;
        const int ss = mm - bb * PLANE;
        float* obase = out + (size_t)bb * (OC * PLANE) + ss;
#pragma unroll
        for (int f = 0; f < 4; ++f) {
#pragma unroll
            for (int i = 0; i < 4; ++i) {
                const int n = n0 + f * 16 + quad * 4 + i;
                obase[(size_t)n * PLANE] = acc[f][g][i];
            }
        }
    }
}

extern "C" void kernel_launch(void* const* d_in, const int* in_sizes, int n_in,
                              void* d_out, int out_size, void* d_ws, size_t ws_size,
                              hipStream_t stream) {
    const float* x    = (const float*)d_in[0];
    const float* W    = (const float*)d_in[1];
    const float* bias = (const float*)d_in[2];
    float* out = (float*)d_out;

    u16* xpad = (u16*)d_ws;
    u16* w3   = xpad + XPAD_ELEMS;

    const int n4 = (XPAD_ELEMS * 2) / 16;   // 1,722,368 uint4
    zero_ws<<<(n4 + 255) / 256, 256, 0, stream>>>((uint4*)xpad, n4);
    pad_tr<<<dim3(HH, BATCH), 256, 0, stream>>>(x, xpad);
    pack_w<<<(W3_ELEMS + 255) / 256, 256, 0, stream>>>(W, w3);

    dim3 grid(784, 2);
    conv_main<<<grid, 256, 0, stream>>>(xpad, w3, bias, out);
}

// Round 4
// 215.095 us; speedup vs baseline: 1.3004x; 1.0554x over previous
//
#include <hip/hip_runtime.h>
#include <hip/hip_bf16.h>
#include <stdint.h>

typedef unsigned short u16;
typedef unsigned int   u32;
typedef __bf16 bf16x8 __attribute__((ext_vector_type(8)));
typedef float  f32x4  __attribute__((ext_vector_type(4)));

#define BATCH 32
#define CIN   128
#define HH    56
#define WW    56
#define OC    256
#define HP    58
#define WP    58
#define PLANE  (HH*WW)    // 3136
#define KDIM   1152       // CIN*9
#define NKT    36         // KDIM/32

#define XPAD_ELEMS (BATCH*HP*WP*CIN)   // NHWC padded bf16: 13,778,944
#define W3_ELEMS   (OC*KDIM)           // 294,912 bf16

#define GLDS16(g, l) __builtin_amdgcn_global_load_lds( \
    (const __attribute__((address_space(1))) void*)(g), \
    (__attribute__((address_space(3))) void*)(l), 16, 0, 0)

// ---- prep 0: zero top/bottom padded rows (h=0 and h=57 per image) ----
__global__ void zero_border(uint4* __restrict__ xp4) {
    int i = blockIdx.x * 256 + threadIdx.x;       // uint4 index
    if (i >= 64 * 928) return;                    // 64 rows x 928 uint4/row
    int row = i / 928;
    int off = i - row * 928;
    int b = row >> 1;
    int h = (row & 1) ? (HP - 1) : 0;
    xp4[((size_t)(b * HP + h) * WP * CIN) / 8 + off] = (uint4){0, 0, 0, 0};
}

// ---- prep 1: NCHW fp32 -> NHWC bf16, interior + left/right borders ----
// block = (h, b); handles one (b, h): 128 ch x 56 w -> padded row of 58 w
__global__ __launch_bounds__(256) void pad_tr(const float* __restrict__ x,
                                              u16* __restrict__ xpad) {
    __shared__ u16 T16[56 * 130];   // [w][c], +2 pad -> bank stride 65 dwords
    const int h = blockIdx.x;
    const int b = blockIdx.y;
    const int tid = threadIdx.x;

    const float* src = x + (size_t)b * CIN * PLANE + h * WW;
#pragma unroll
    for (int j = 0; j < 28; ++j) {              // 28*256 = 7168 = 128*56
        int flat = j * 256 + tid;
        int c = flat / 56;
        int w = flat - c * 56;
        float v = src[(size_t)c * PLANE + w];
        __hip_bfloat16 bv = __float2bfloat16(v);
        T16[w * 130 + c] = *(u16*)&bv;
    }
    __syncthreads();

    // write full padded row: 58 positions x 128 ch = 928 uint4
    const u32* T32 = (const u32*)T16;
    uint4* dst = (uint4*)(xpad + (size_t)(b * HP + h + 1) * WP * CIN);
#pragma unroll
    for (int j = 0; j < 4; ++j) {
        int g = j * 256 + tid;
        if (g < 928) {
            int wp = g >> 4, cq = g & 15;       // 16 uint4 = 128 ch per wp
            uint4 v = (uint4){0, 0, 0, 0};
            if (wp >= 1 && wp <= 56) {
                int w = wp - 1;
                v.x = T32[w * 65 + cq * 4 + 0];
                v.y = T32[w * 65 + cq * 4 + 1];
                v.z = T32[w * 65 + cq * 4 + 2];
                v.w = T32[w * 65 + cq * 4 + 3];
            }
            dst[g] = v;
        }
    }
}

// ---- prep 2: W[OC][C*9] fp32 -> bf16 tiled w3[nt][kt][ni128][ci32] ----
// k ordering: k = r*128 + c  (r = kh*3+kw)
__global__ void pack_w(const float* __restrict__ W, u16* __restrict__ w3) {
    int o = blockIdx.x * blockDim.x + threadIdx.x;
    if (o >= W3_ELEMS) return;
    int nt   = o / (NKT * 4096);
    int rem  = o - nt * (NKT * 4096);
    int kt   = rem / 4096;
    int rem2 = rem - kt * 4096;
    int ni   = rem2 >> 5;
    int ci   = rem2 & 31;
    int n = nt * 128 + ni;
    int r = kt >> 2;                 // 0..8
    int c = ((kt & 3) << 5) + ci;    // 0..127
    float val = W[n * KDIM + c * 9 + r];
    __hip_bfloat16 bv = __float2bfloat16(val);
    w3[o] = *(u16*)&bv;
}

// ---------------- main: implicit GEMM, 128x128 tile, BK=32 ----------------
// Ping-pong LDS double buffer, ONE __syncthreads per kt: DMA(kt+1) issued
// after barrier(kt), overlapped by compute(kt); drained at barrier(kt+1).
// LDS chunk-rotation swizzle: chunk q of row r stored at position
// (q + (r>>1)) & 3  -> frag ds_read_b128 goes from 8-way to 2-way (free)
// bank aliasing. Rotation is folded into the per-lane GLOBAL fetch address;
// LDS DMA dst stays wave-uniform-base + lane*16 as required.
__global__ __launch_bounds__(256) void conv_main(
    const u16* __restrict__ xpad,
    const u16* __restrict__ w3,
    const float* __restrict__ bias,
    float* __restrict__ out)
{
    __shared__ __align__(16) u16 As[2][128 * 32];  // [buf][ni][ci] 8 KB each
    __shared__ __align__(16) u16 Bs[2][128 * 32];  // [buf][mi][ci]

    const int tid  = threadIdx.x;
    const int lane = tid & 63;
    const int wv   = tid >> 6;
    const int m0   = blockIdx.x * 128;
    const int nt   = blockIdx.y;

    // staging: granule lane -> row srow, chunk position sc; fetch global
    // chunk (sc - rot(row)) & 3 so that LDS position sc holds rotated data
    const int srow = lane >> 2;
    const int sc   = lane & 3;
    size_t abase[2], bbase[2];
#pragma unroll
    for (int i = 0; i < 2; ++i) {
        int rowid = wv * 32 + i * 16 + srow;
        int q = (sc - ((rowid >> 1) & 3)) & 3;
        abase[i] = (size_t)rowid * 64 + q * 16;
        int m  = m0 + rowid;
        int bb = m / PLANE;
        int s  = m - bb * PLANE;
        int hh = s / WW;
        int ww = s - hh * WW;
        bbase[i] = ((size_t)((bb * HP + hh) * WP + ww) * CIN) * 2 + q * 16;
    }
    const char* w3t = (const char*)(w3 + (size_t)nt * (NKT * 4096));
    const char* xb  = (const char*)xpad;
    char* AsW[2] = { (char*)As[0] + wv * 2048, (char*)As[1] + wv * 2048 };
    char* BsW[2] = { (char*)Bs[0] + wv * 2048, (char*)Bs[1] + wv * 2048 };

    const int wn = wv >> 1, wm = wv & 1;
    const int l16 = lane & 15, quad = lane >> 4;

    // frag read offsets (bytes), rotation applied; loop-invariant
    int aoff[4], boff[4];
#pragma unroll
    for (int f = 0; f < 4; ++f) {
        int ra = wn * 64 + f * 16 + l16;
        aoff[f] = ra * 64 + ((quad + (ra >> 1)) & 3) * 16;
        int rb = wm * 64 + f * 16 + l16;
        boff[f] = rb * 64 + ((quad + (rb >> 1)) & 3) * 16;
    }

    f32x4 acc[4][4];
#pragma unroll
    for (int f = 0; f < 4; ++f) {
        f32x4 bv = *(const f32x4*)&bias[nt * 128 + wn * 64 + f * 16 + quad * 4];
#pragma unroll
        for (int g = 0; g < 4; ++g) acc[f][g] = bv;
    }

    auto issue = [&](int kt) {
        const int buf = kt & 1;
        const int r  = kt >> 2;
        const int cc = kt & 3;
        const int kh = r / 3;
        const int kw = r - kh * 3;
        const size_t xoff = ((size_t)(kh * WP + kw) * CIN + cc * 32) * 2;
#pragma unroll
        for (int i = 0; i < 2; ++i) {
            GLDS16(w3t + (size_t)kt * 8192 + abase[i], AsW[buf] + i * 1024);
            GLDS16(xb + bbase[i] + xoff,               BsW[buf] + i * 1024);
        }
    };

    issue(0);
#pragma unroll
    for (int kt = 0; kt < NKT; ++kt) {
        __syncthreads();                    // drains DMA(kt); frees other buf
        if (kt + 1 < NKT) issue(kt + 1);    // in flight across compute(kt)

        const char* Ab = (const char*)As[kt & 1];
        const char* Bb = (const char*)Bs[kt & 1];
        bf16x8 af[4], bfr[4];
#pragma unroll
        for (int f = 0; f < 4; ++f)
            af[f] = *(const bf16x8*)(Ab + aoff[f]);
#pragma unroll
        for (int g = 0; g < 4; ++g)
            bfr[g] = *(const bf16x8*)(Bb + boff[g]);

#pragma unroll
        for (int f = 0; f < 4; ++f)
#pragma unroll
            for (int g = 0; g < 4; ++g)
                acc[f][g] = __builtin_amdgcn_mfma_f32_16x16x32_bf16(
                    af[f], bfr[g], acc[f][g], 0, 0, 0);
    }

    // epilogue: D row = oc (quad*4+reg), col = spatial m (lane&15)
    const int n0 = nt * 128 + wn * 64;
#pragma unroll
    for (int g = 0; g < 4; ++g) {
        const int mm = m0 + wm * 64 + g * 16 + l16;
        const int bb = mm / PLANE;
        const int ss = mm - bb * PLANE;
        float* obase = out + (size_t)bb * (OC * PLANE) + ss;
#pragma unroll
        for (int f = 0; f < 4; ++f) {
#pragma unroll
            for (int i = 0; i < 4; ++i) {
                const int n = n0 + f * 16 + quad * 4 + i;
                obase[(size_t)n * PLANE] = acc[f][g][i];
            }
        }
    }
}

extern "C" void kernel_launch(void* const* d_in, const int* in_sizes, int n_in,
                              void* d_out, int out_size, void* d_ws, size_t ws_size,
                              hipStream_t stream) {
    const float* x    = (const float*)d_in[0];
    const float* W    = (const float*)d_in[1];
    const float* bias = (const float*)d_in[2];
    float* out = (float*)d_out;

    u16* xpad = (u16*)d_ws;
    u16* w3   = xpad + XPAD_ELEMS;

    zero_border<<<232, 256, 0, stream>>>((uint4*)xpad);
    pad_tr<<<dim3(HH, BATCH), 256, 0, stream>>>(x, xpad);
    pack_w<<<(W3_ELEMS + 255) / 256, 256, 0, stream>>>(W, w3);

    dim3 grid(784, 2);
    conv_main<<<grid, 256, 0, stream>>>(xpad, w3, bias, out);
}